// Round 6
// baseline (439.125 us; speedup 1.0000x reference)
//
#include <hip/hip_runtime.h>
#include <hip/hip_bf16.h>

#define HID 128
#define BSH 6            // 64 nodes per bucket
#define MAXBUCK 2048     // >= ceil(n/64); n=100000 -> 1563
#define NTILE 8          // column tiles: 16 cols (32 B) each, 3.2 MB per tile

__device__ __forceinline__ float b2f(unsigned short u) {
    union { unsigned i; float f; } v; v.i = ((unsigned)u) << 16; return v.f;
}
__device__ __forceinline__ unsigned short f2b(float f) {
    unsigned u = __float_as_uint(f);
    return (unsigned short)((u + 0x7fffu + ((u >> 16) & 1u)) >> 16);  // RNE
}

// ---------------- zero bucket counters ----------------
__global__ void zero_kernel(unsigned* __restrict__ p, int n) {
    int i = blockIdx.x * blockDim.x + threadIdx.x;
    if (i < n) p[i] = 0u;
}

// ---------------- K1: bucket histogram (LDS-aggregated) ----------------
__global__ __launch_bounds__(256) void bincount_kernel(const int* __restrict__ ei,
                                                       unsigned* __restrict__ bcount,
                                                       int E, int n, int nbuck) {
    __shared__ unsigned hist[MAXBUCK];
    for (int i = threadIdx.x; i < nbuck; i += 256) hist[i] = 0u;
    __syncthreads();
    int i = blockIdx.x * 256 + threadIdx.x, stride = gridDim.x * 256;
    for (; i < E; i += stride) {
        int dst = ei[(size_t)E + i];
        if ((unsigned)dst < (unsigned)n) atomicAdd(&hist[dst >> BSH], 1u);
    }
    __syncthreads();
    for (int b = threadIdx.x; b < nbuck; b += 256) {
        unsigned c = hist[b];
        if (c) atomicAdd(&bcount[b], c);
    }
}

// ---------------- K2: scan of bucket counts (single block) ----------------
__global__ __launch_bounds__(1024) void bscan_kernel(const unsigned* __restrict__ bcount,
                                                     unsigned* __restrict__ boff,
                                                     unsigned* __restrict__ bwoff,
                                                     unsigned* __restrict__ off,
                                                     int nbuck, int n) {
    __shared__ unsigned sums[1024];
    int t = threadIdx.x;
    int chunk = (nbuck + 1023) >> 10;
    int beg = min(t * chunk, nbuck), end = min(beg + chunk, nbuck);
    unsigned local = 0;
    for (int i = beg; i < end; ++i) local += bcount[i];
    sums[t] = local;
    __syncthreads();
    for (int d = 1; d < 1024; d <<= 1) {
        unsigned v = (t >= d) ? sums[t - d] : 0u;
        __syncthreads();
        sums[t] += v;
        __syncthreads();
    }
    unsigned run = (t > 0) ? sums[t - 1] : 0u;
    for (int i = beg; i < end; ++i) { boff[i] = run; bwoff[i] = run; run += bcount[i]; }
    if (t == 1023) { boff[nbuck] = sums[1023]; off[n] = sums[1023]; }
}

// ---------------- K3: bin-scatter packed edges into bucket runs ----------------
// binned[pos] = (dst&63)<<20 | src   (src < 2^17)
__global__ __launch_bounds__(256) void binscatter_kernel(const int* __restrict__ ei,
                                                         unsigned* __restrict__ bwoff,
                                                         unsigned* __restrict__ binned,
                                                         int E, int n, int nbuck) {
    __shared__ unsigned hist[MAXBUCK];
    __shared__ unsigned base[MAXBUCK];
    int nb = gridDim.x;
    int chunk = (E + nb - 1) / nb;
    int beg = blockIdx.x * chunk, end = min(E, beg + chunk);
    for (int i = threadIdx.x; i < nbuck; i += 256) hist[i] = 0u;
    __syncthreads();
    for (int i = beg + threadIdx.x; i < end; i += 256) {
        int dst = ei[(size_t)E + i];
        if ((unsigned)dst < (unsigned)n) atomicAdd(&hist[dst >> BSH], 1u);
    }
    __syncthreads();
    for (int b = threadIdx.x; b < nbuck; b += 256) {
        unsigned c = hist[b];
        base[b] = c ? atomicAdd(&bwoff[b], c) : 0u;
        hist[b] = 0u;
    }
    __syncthreads();
    for (int i = beg + threadIdx.x; i < end; i += 256) {
        int s = ei[i];
        int dst = ei[(size_t)E + i];
        if ((unsigned)dst >= (unsigned)n) continue;
        unsigned ss = (unsigned)min(max(s, 0), n - 1);
        int b = dst >> BSH;
        unsigned r = atomicAdd(&hist[b], 1u);
        binned[base[b] + r] = ss | ((unsigned)(dst & ((1 << BSH) - 1)) << 20);
    }
}

// ---------------- K4: per-bucket CSR finalize (off, dinv, srcs) ----------------
__global__ __launch_bounds__(256) void csrbuild_kernel(const unsigned* __restrict__ binned,
                                                       const unsigned* __restrict__ boff,
                                                       unsigned* __restrict__ off,
                                                       float* __restrict__ dinv,
                                                       unsigned* __restrict__ srcs,
                                                       int n) {
    __shared__ unsigned hist[64];
    __shared__ unsigned nodeoff[64];
    int b = blockIdx.x;
    unsigned s0 = boff[b], s1 = boff[b + 1];
    int t = threadIdx.x;
    if (t < 64) hist[t] = 0u;
    __syncthreads();
    for (unsigned j = s0 + t; j < s1; j += 256) atomicAdd(&hist[binned[j] >> 20], 1u);
    __syncthreads();
    if (t < 64) {  // wave 0: 64-lane shuffle scan
        unsigned cnt = hist[t];
        unsigned x = cnt;
        for (int d = 1; d < 64; d <<= 1) {
            unsigned v = __shfl_up(x, d, 64);
            if (t >= d) x += v;
        }
        unsigned excl = x - cnt;
        nodeoff[t] = excl;
        hist[t] = 0u;
        int node = (b << BSH) + t;
        if (node < n) {
            off[node] = s0 + excl;
            dinv[node] = rsqrtf((float)(cnt + 1u));  // +1 self-loop
        }
    }
    __syncthreads();
    for (unsigned j = s0 + t; j < s1; j += 256) {
        unsigned p = binned[j];
        unsigned dl = p >> 20, s = p & 0xFFFFFu;
        unsigned r = atomicAdd(&hist[dl], 1u);
        srcs[s0 + nodeoff[dl] + r] = s;
    }
}

// ---------------- h' = dinv * ((x + h_cur) @ W[:, 0:128]) , column-tiled bf16 out ----------------
// hp layout: [NTILE][n][16]  (tile = col/16)
__global__ __launch_bounds__(256) void gemm_kernel(const float* __restrict__ x,
                                                   const float* __restrict__ hc,
                                                   const float* __restrict__ W,
                                                   const float* __restrict__ dinv,
                                                   unsigned short* __restrict__ hp, int n) {
    __shared__ float A[64 * 132];
    int tid = threadIdx.x;
    int r0 = blockIdx.x * 64;

    for (int i = tid; i < 2048; i += 256) {
        int row = i >> 5;
        int c4 = (i & 31) * 4;
        int grow = r0 + row;
        float4 v;
        if (grow < n) {
            float4 a = *(const float4*)(x + (size_t)grow * HID + c4);
            float4 bb = *(const float4*)(hc + (size_t)grow * HID + c4);
            v = make_float4(a.x + bb.x, a.y + bb.y, a.z + bb.z, a.w + bb.w);
        } else {
            v = make_float4(0.f, 0.f, 0.f, 0.f);
        }
        *(float4*)(&A[row * 132 + c4]) = v;
    }
    __syncthreads();

    int cg = tid & 31;
    int c4 = cg * 4;
    int rg = tid >> 5;
    float acc[8][4];
#pragma unroll
    for (int r = 0; r < 8; ++r) {
        acc[r][0] = 0.f; acc[r][1] = 0.f; acc[r][2] = 0.f; acc[r][3] = 0.f;
    }

#pragma unroll 4
    for (int k = 0; k < 128; ++k) {
        float4 w = *(const float4*)(W + (size_t)k * 512 + c4);
#pragma unroll
        for (int r = 0; r < 8; ++r) {
            float a = A[(rg * 8 + r) * 132 + k];
            acc[r][0] += a * w.x;
            acc[r][1] += a * w.y;
            acc[r][2] += a * w.z;
            acc[r][3] += a * w.w;
        }
    }

    size_t tile = (size_t)(c4 >> 4);
    int cin = c4 & 15;
#pragma unroll
    for (int r = 0; r < 8; ++r) {
        int grow = r0 + rg * 8 + r;
        if (grow < n) {
            float di = dinv[grow];
            unsigned long long pack =
                (unsigned long long)f2b(di * acc[r][0]) |
                ((unsigned long long)f2b(di * acc[r][1]) << 16) |
                ((unsigned long long)f2b(di * acc[r][2]) << 32) |
                ((unsigned long long)f2b(di * acc[r][3]) << 48);
            *(unsigned long long*)(hp + tile * (size_t)n * 16 + (size_t)grow * 16 + cin) = pack;
        }
    }
}

// ---------------- aggregate, column-tiled & XCD-pinned ----------------
// tile = blockIdx & 7 -> lands on a fixed XCD (round-robin dispatch), so each
// XCD gathers only from its own 3.2 MB L2-resident tile of h'.
// Wave = 1 node: lanes = 8 edge-groups x 8 col-pairs; shfl_xor reduce over groups.
__global__ __launch_bounds__(256) void agg_tiled_kernel(const unsigned* __restrict__ srcs,
                                                        const unsigned* __restrict__ off,
                                                        const float* __restrict__ dinv,
                                                        const unsigned short* __restrict__ hp,
                                                        const float* __restrict__ b,
                                                        float* __restrict__ out, int n) {
    int blk = blockIdx.x;
    int t = blk & 7;
    int g = blk >> 3;
    int w = threadIdx.x >> 6;
    int d = g * 4 + w;
    if (d >= n) return;
    int lane = threadIdx.x & 63;
    int eg = lane >> 3;      // edge group 0..7
    int cp = lane & 7;       // col pair 0..7 (2 cols each)
    const unsigned short* hpt = hp + (size_t)t * n * 16;

    unsigned beg = off[d], end = off[d + 1];
    float ax = 0.f, ay = 0.f;
    unsigned i = beg;
    for (; i + 16 <= end; i += 16) {
        unsigned s0 = srcs[i + eg];
        unsigned s1 = srcs[i + 8 + eg];
        ushort2 v0 = *(const ushort2*)(hpt + (size_t)s0 * 16 + cp * 2);
        ushort2 v1 = *(const ushort2*)(hpt + (size_t)s1 * 16 + cp * 2);
        ax += b2f(v0.x) + b2f(v1.x);
        ay += b2f(v0.y) + b2f(v1.y);
    }
    for (; i + 8 <= end; i += 8) {
        unsigned s0 = srcs[i + eg];
        ushort2 v0 = *(const ushort2*)(hpt + (size_t)s0 * 16 + cp * 2);
        ax += b2f(v0.x);
        ay += b2f(v0.y);
    }
    unsigned rem = end - i;
    if ((unsigned)eg < rem) {
        unsigned s0 = srcs[i + eg];
        ushort2 v0 = *(const ushort2*)(hpt + (size_t)s0 * 16 + cp * 2);
        ax += b2f(v0.x);
        ay += b2f(v0.y);
    }
    if (eg == 0) {  // self-loop: + h'[d]
        ushort2 vd = *(const ushort2*)(hpt + (size_t)d * 16 + cp * 2);
        ax += b2f(vd.x);
        ay += b2f(vd.y);
    }
    // reduce over the 8 edge groups
    ax += __shfl_xor(ax, 8);  ay += __shfl_xor(ay, 8);
    ax += __shfl_xor(ax, 16); ay += __shfl_xor(ay, 16);
    ax += __shfl_xor(ax, 32); ay += __shfl_xor(ay, 32);

    if (eg == 0) {
        float di = dinv[d];
        int col = t * 16 + cp * 2;
        float2 bb = *(const float2*)(b + col);
        float2 res = make_float2(di * ax + bb.x, di * ay + bb.y);
        *(float2*)(out + (size_t)d * HID + col) = res;
    }
}

extern "C" void kernel_launch(void* const* d_in, const int* in_sizes, int n_in,
                              void* d_out, int out_size, void* d_ws, size_t ws_size,
                              hipStream_t stream) {
    const float* x = (const float*)d_in[0];
    const int* ei = (const int*)d_in[1];       // int32 per harness contract
    const float* hc = (const float*)d_in[2];
    // d_in[3] = c_cur unused
    const float* W = (const float*)d_in[4];
    const float* b = (const float*)d_in[5];
    float* out = (float*)d_out;

    int n = in_sizes[0] / HID;      // 100000
    int E = in_sizes[1] / 2;        // 3200000
    int nbuck = (n + 63) >> BSH;    // 1563 (<= MAXBUCK)

    // workspace layout (16B-aligned), total ~39.2 MB
    char* ws = (char*)d_ws;
    unsigned* bcount = (unsigned*)(ws);                  // 8KB region
    unsigned* boff   = (unsigned*)(ws + 8192);           // 8KB region (nbuck+1)
    unsigned* bwoff  = (unsigned*)(ws + 16384);          // 8KB region
    unsigned* off    = (unsigned*)(ws + 24576);          // (n+1)*4
    float*    dinv   = (float*)   (ws + 424592);         // n*4
    unsigned* srcs   = (unsigned*)(ws + 824592);         // E*4 = 12.8MB
    unsigned short* hp = (unsigned short*)(ws + 13624592); // [8][n][16] bf16 = 25.6MB

    // d_out doubles as scratch for the packed binned edges (12.8MB << 51.2MB);
    // agg_tiled_kernel fully overwrites d_out afterwards.
    unsigned* binned = (unsigned*)d_out;

    zero_kernel<<<(nbuck + 255) / 256, 256, 0, stream>>>(bcount, nbuck);
    bincount_kernel<<<512, 256, 0, stream>>>(ei, bcount, E, n, nbuck);
    bscan_kernel<<<1, 1024, 0, stream>>>(bcount, boff, bwoff, off, nbuck, n);
    binscatter_kernel<<<256, 256, 0, stream>>>(ei, bwoff, binned, E, n, nbuck);
    csrbuild_kernel<<<nbuck, 256, 0, stream>>>(binned, boff, off, dinv, srcs, n);

    int gemm_blocks = (n + 63) / 64;
    gemm_kernel<<<gemm_blocks, 256, 0, stream>>>(x, hc, W, dinv, hp, n);

    int agg_blocks = NTILE * ((n + 3) / 4);   // 8 tiles x 4 nodes per block
    agg_tiled_kernel<<<agg_blocks, 256, 0, stream>>>(srcs, off, dinv, hp, b, out, n);
}

// Round 7
// 285.566 us; speedup vs baseline: 1.5377x; 1.5377x over previous
//
#include <hip/hip_runtime.h>
#include <hip/hip_bf16.h>

#define HID 128
#define BSH 6            // 64 nodes per bucket
#define MAXBUCK 2048     // >= ceil(n/64); n=100000 -> 1563

__device__ __forceinline__ float b2f(unsigned short u) {
    union { unsigned i; float f; } v; v.i = ((unsigned)u) << 16; return v.f;
}
__device__ __forceinline__ unsigned short f2b(float f) {
    unsigned u = __float_as_uint(f);
    return (unsigned short)((u + 0x7fffu + ((u >> 16) & 1u)) >> 16);  // RNE
}

// ---------------- zero bucket counters ----------------
__global__ void zero_kernel(unsigned* __restrict__ p, int n) {
    int i = blockIdx.x * blockDim.x + threadIdx.x;
    if (i < n) p[i] = 0u;
}

// ---------------- K1: bucket histogram (LDS-aggregated) ----------------
__global__ __launch_bounds__(256) void bincount_kernel(const int* __restrict__ ei,
                                                       unsigned* __restrict__ bcount,
                                                       int E, int n, int nbuck) {
    __shared__ unsigned hist[MAXBUCK];
    for (int i = threadIdx.x; i < nbuck; i += 256) hist[i] = 0u;
    __syncthreads();
    int i = blockIdx.x * 256 + threadIdx.x, stride = gridDim.x * 256;
    for (; i < E; i += stride) {
        int dst = ei[(size_t)E + i];
        if ((unsigned)dst < (unsigned)n) atomicAdd(&hist[dst >> BSH], 1u);
    }
    __syncthreads();
    for (int b = threadIdx.x; b < nbuck; b += 256) {
        unsigned c = hist[b];
        if (c) atomicAdd(&bcount[b], c);
    }
}

// ---------------- K2: scan of bucket counts (single block) ----------------
__global__ __launch_bounds__(1024) void bscan_kernel(const unsigned* __restrict__ bcount,
                                                     unsigned* __restrict__ boff,
                                                     unsigned* __restrict__ bwoff,
                                                     unsigned* __restrict__ off,
                                                     int nbuck, int n) {
    __shared__ unsigned sums[1024];
    int t = threadIdx.x;
    int chunk = (nbuck + 1023) >> 10;
    int beg = min(t * chunk, nbuck), end = min(beg + chunk, nbuck);
    unsigned local = 0;
    for (int i = beg; i < end; ++i) local += bcount[i];
    sums[t] = local;
    __syncthreads();
    for (int d = 1; d < 1024; d <<= 1) {
        unsigned v = (t >= d) ? sums[t - d] : 0u;
        __syncthreads();
        sums[t] += v;
        __syncthreads();
    }
    unsigned run = (t > 0) ? sums[t - 1] : 0u;
    for (int i = beg; i < end; ++i) { boff[i] = run; bwoff[i] = run; run += bcount[i]; }
    if (t == 1023) { boff[nbuck] = sums[1023]; off[n] = sums[1023]; }
}

// ---------------- K3 (fused): binscatter (blocks 0..nsb-1) + gemm (rest) ----------------
// binned[pos] = (dst&63)<<20 | src ; gemm: hp = (x+h_cur)@W[:,0:128] as bf16, UNSCALED
__global__ __launch_bounds__(256) void phase3_kernel(const int* __restrict__ ei,
                                                     unsigned* __restrict__ bwoff,
                                                     unsigned* __restrict__ binned,
                                                     const float* __restrict__ x,
                                                     const float* __restrict__ hc,
                                                     const float* __restrict__ W,
                                                     unsigned short* __restrict__ hp,
                                                     int E, int n, int nbuck, int nsb) {
    __shared__ union {
        struct { unsigned hist[MAXBUCK]; unsigned base[MAXBUCK]; } bs;
        float A[64 * 132];
    } sm;

    if (blockIdx.x < nsb) {
        // ---- binscatter body ----
        int chunk = (E + nsb - 1) / nsb;
        int beg = blockIdx.x * chunk, end = min(E, beg + chunk);
        for (int i = threadIdx.x; i < nbuck; i += 256) sm.bs.hist[i] = 0u;
        __syncthreads();
        for (int i = beg + threadIdx.x; i < end; i += 256) {
            int dst = ei[(size_t)E + i];
            if ((unsigned)dst < (unsigned)n) atomicAdd(&sm.bs.hist[dst >> BSH], 1u);
        }
        __syncthreads();
        for (int b = threadIdx.x; b < nbuck; b += 256) {
            unsigned c = sm.bs.hist[b];
            sm.bs.base[b] = c ? atomicAdd(&bwoff[b], c) : 0u;
            sm.bs.hist[b] = 0u;
        }
        __syncthreads();
        for (int i = beg + threadIdx.x; i < end; i += 256) {
            int s = ei[i];
            int dst = ei[(size_t)E + i];
            if ((unsigned)dst >= (unsigned)n) continue;
            unsigned ss = (unsigned)min(max(s, 0), n - 1);
            int b = dst >> BSH;
            unsigned r = atomicAdd(&sm.bs.hist[b], 1u);
            binned[sm.bs.base[b] + r] = ss | ((unsigned)(dst & ((1 << BSH) - 1)) << 20);
        }
    } else {
        // ---- gemm body ----
        int tid = threadIdx.x;
        int r0 = (blockIdx.x - nsb) * 64;

        for (int i = tid; i < 2048; i += 256) {
            int row = i >> 5;
            int c4 = (i & 31) * 4;
            int grow = r0 + row;
            float4 v;
            if (grow < n) {
                float4 a = *(const float4*)(x + (size_t)grow * HID + c4);
                float4 bb = *(const float4*)(hc + (size_t)grow * HID + c4);
                v = make_float4(a.x + bb.x, a.y + bb.y, a.z + bb.z, a.w + bb.w);
            } else {
                v = make_float4(0.f, 0.f, 0.f, 0.f);
            }
            *(float4*)(&sm.A[row * 132 + c4]) = v;
        }
        __syncthreads();

        int cg = tid & 31;
        int c4 = cg * 4;
        int rg = tid >> 5;
        float acc[8][4];
#pragma unroll
        for (int r = 0; r < 8; ++r) {
            acc[r][0] = 0.f; acc[r][1] = 0.f; acc[r][2] = 0.f; acc[r][3] = 0.f;
        }

#pragma unroll 4
        for (int k = 0; k < 128; ++k) {
            float4 w = *(const float4*)(W + (size_t)k * 512 + c4);
#pragma unroll
            for (int r = 0; r < 8; ++r) {
                float a = sm.A[(rg * 8 + r) * 132 + k];
                acc[r][0] += a * w.x;
                acc[r][1] += a * w.y;
                acc[r][2] += a * w.z;
                acc[r][3] += a * w.w;
            }
        }

#pragma unroll
        for (int r = 0; r < 8; ++r) {
            int grow = r0 + rg * 8 + r;
            if (grow < n) {
                unsigned long long pack =
                    (unsigned long long)f2b(acc[r][0]) |
                    ((unsigned long long)f2b(acc[r][1]) << 16) |
                    ((unsigned long long)f2b(acc[r][2]) << 32) |
                    ((unsigned long long)f2b(acc[r][3]) << 48);
                *(unsigned long long*)(hp + (size_t)grow * HID + c4) = pack;
            }
        }
    }
}

// ---------------- K4: per-bucket CSR finalize + in-place dinv scaling of hp ----------------
__global__ __launch_bounds__(256) void csrbuild_kernel(const unsigned* __restrict__ binned,
                                                       const unsigned* __restrict__ boff,
                                                       unsigned* __restrict__ off,
                                                       float* __restrict__ dinv,
                                                       unsigned* __restrict__ srcs,
                                                       unsigned short* __restrict__ hp,
                                                       int n) {
    __shared__ unsigned hist[64];
    __shared__ unsigned nodeoff[64];
    __shared__ float sdinv[64];
    int b = blockIdx.x;
    unsigned s0 = boff[b], s1 = boff[b + 1];
    int t = threadIdx.x;
    if (t < 64) hist[t] = 0u;
    __syncthreads();
    for (unsigned j = s0 + t; j < s1; j += 256) atomicAdd(&hist[binned[j] >> 20], 1u);
    __syncthreads();
    if (t < 64) {  // wave 0: 64-lane shuffle scan
        unsigned cnt = hist[t];
        unsigned x = cnt;
        for (int d = 1; d < 64; d <<= 1) {
            unsigned v = __shfl_up(x, d, 64);
            if (t >= d) x += v;
        }
        unsigned excl = x - cnt;
        nodeoff[t] = excl;
        hist[t] = 0u;
        float dv = rsqrtf((float)(cnt + 1u));  // +1 self-loop
        sdinv[t] = dv;
        int node = (b << BSH) + t;
        if (node < n) {
            off[node] = s0 + excl;
            dinv[node] = dv;
        }
    }
    __syncthreads();
    for (unsigned j = s0 + t; j < s1; j += 256) {
        unsigned p = binned[j];
        unsigned dl = p >> 20, s = p & 0xFFFFFu;
        unsigned r = atomicAdd(&hist[dl], 1u);
        srcs[s0 + nodeoff[dl] + r] = s;
    }
    // scale this bucket's hp rows by dinv (64 rows x 64 u32 = 4096 u32)
    int node0 = b << BSH;
    unsigned* hp32 = (unsigned*)hp;
    for (int idx = t; idx < 4096; idx += 256) {
        int nd = node0 + (idx >> 6);
        if (nd < n) {
            float dv = sdinv[idx >> 6];
            unsigned* p = hp32 + (size_t)nd * 64 + (idx & 63);
            unsigned u = *p;
            float lo = b2f((unsigned short)(u & 0xFFFFu)) * dv;
            float hi = b2f((unsigned short)(u >> 16)) * dv;
            *p = (unsigned)f2b(lo) | ((unsigned)f2b(hi) << 16);
        }
    }
}

// ---------------- aggregate: wave=node, 2 cols/lane, 16-deep MLP, dinv pre-folded ----------------
__global__ __launch_bounds__(256) void agg_kernel(const unsigned* __restrict__ srcs,
                                                  const unsigned* __restrict__ off,
                                                  const float* __restrict__ dinv,
                                                  const unsigned short* __restrict__ hp,
                                                  const float* __restrict__ b,
                                                  float* __restrict__ out, int n) {
    int wid = (int)((blockIdx.x * (size_t)blockDim.x + threadIdx.x) >> 6);
    int lane = threadIdx.x & 63;
    if (wid >= n) return;
    unsigned beg = off[wid], end = off[wid + 1];
    int c = lane * 2;
    float ax = 0.f, ay = 0.f;

    unsigned i = beg;
    for (; i + 16 <= end; i += 16) {
        unsigned s[16]; ushort2 v[16];
#pragma unroll
        for (int k = 0; k < 16; ++k) s[k] = srcs[i + k];
#pragma unroll
        for (int k = 0; k < 16; ++k) v[k] = *(const ushort2*)(hp + (size_t)s[k] * HID + c);
#pragma unroll
        for (int k = 0; k < 16; ++k) { ax += b2f(v[k].x); ay += b2f(v[k].y); }
    }
    if (i < end) {
        unsigned last = end - 1;
        unsigned s[16]; ushort2 v[16]; float m[16];
#pragma unroll
        for (int k = 0; k < 16; ++k) {
            unsigned j = i + k;
            m[k] = (j < end) ? 1.f : 0.f;
            s[k] = srcs[j < end ? j : last];
        }
#pragma unroll
        for (int k = 0; k < 16; ++k) v[k] = *(const ushort2*)(hp + (size_t)s[k] * HID + c);
#pragma unroll
        for (int k = 0; k < 16; ++k) {
            ax = fmaf(m[k], b2f(v[k].x), ax);
            ay = fmaf(m[k], b2f(v[k].y), ay);
        }
    }

    // self-loop: hp[wid] is dinv[wid]*h[wid]
    ushort2 vd = *(const ushort2*)(hp + (size_t)wid * HID + c);
    ax += b2f(vd.x);
    ay += b2f(vd.y);

    float di = dinv[wid];
    float2 bb = *(const float2*)(b + c);
    float2 res = make_float2(di * ax + bb.x, di * ay + bb.y);
    *(float2*)(out + (size_t)wid * HID + c) = res;
}

extern "C" void kernel_launch(void* const* d_in, const int* in_sizes, int n_in,
                              void* d_out, int out_size, void* d_ws, size_t ws_size,
                              hipStream_t stream) {
    const float* x = (const float*)d_in[0];
    const int* ei = (const int*)d_in[1];       // int32 per harness contract
    const float* hc = (const float*)d_in[2];
    // d_in[3] = c_cur unused
    const float* W = (const float*)d_in[4];
    const float* b = (const float*)d_in[5];
    float* out = (float*)d_out;

    int n = in_sizes[0] / HID;      // 100000
    int E = in_sizes[1] / 2;        // 3200000
    int nbuck = (n + 63) >> BSH;    // 1563 (<= MAXBUCK)
    int nsb = 256;                  // binscatter blocks in fused phase3

    // workspace layout (16B-aligned), total ~39.2 MB
    char* ws = (char*)d_ws;
    unsigned* bcount = (unsigned*)(ws);                    // 8KB region
    unsigned* boff   = (unsigned*)(ws + 8192);             // 8KB region (nbuck+1)
    unsigned* bwoff  = (unsigned*)(ws + 16384);            // 8KB region
    unsigned* off    = (unsigned*)(ws + 24576);            // (n+1)*4
    float*    dinv   = (float*)   (ws + 424592);           // n*4
    unsigned* srcs   = (unsigned*)(ws + 824592);           // E*4 = 12.8MB
    unsigned short* hp = (unsigned short*)(ws + 13624592); // [n][128] bf16 = 25.6MB

    // d_out doubles as scratch for the packed binned edges (12.8MB << 51.2MB);
    // agg_kernel fully overwrites d_out afterwards.
    unsigned* binned = (unsigned*)d_out;

    zero_kernel<<<(nbuck + 255) / 256, 256, 0, stream>>>(bcount, nbuck);
    bincount_kernel<<<512, 256, 0, stream>>>(ei, bcount, E, n, nbuck);
    bscan_kernel<<<1, 1024, 0, stream>>>(bcount, boff, bwoff, off, nbuck, n);

    int gemm_blocks = (n + 63) / 64;   // 1563
    phase3_kernel<<<nsb + gemm_blocks, 256, 0, stream>>>(ei, bwoff, binned, x, hc, W, hp,
                                                         E, n, nbuck, nsb);
    csrbuild_kernel<<<nbuck, 256, 0, stream>>>(binned, boff, off, dinv, srcs, hp, n);

    int agg_blocks = (n + 3) / 4;   // 4 waves (nodes) per 256-thread block
    agg_kernel<<<agg_blocks, 256, 0, stream>>>(srcs, off, dinv, hp, b, out, n);
}